// Round 2
// baseline (1222.550 us; speedup 1.0000x reference)
//
#include <hip/hip_runtime.h>

#define HB 32
#define NBv 33
#define NB3 35937
#define BN_EPS 1e-5f

using short8 = __attribute__((ext_vector_type(8))) short;
using f32x4  = __attribute__((ext_vector_type(4))) float;
using US = unsigned short;

__device__ __forceinline__ unsigned fenc(float f){ unsigned u=__float_as_uint(f); return (u&0x80000000u)? ~u : (u|0x80000000u); }
__device__ __forceinline__ float fdec(unsigned e){ return (e&0x80000000u)? __uint_as_float(e&0x7fffffffu) : __uint_as_float(~e); }
__device__ __forceinline__ US f2bf(float f){ unsigned u=__float_as_uint(f); return (US)((u + 0x7fffu + ((u>>16)&1u))>>16); }
__device__ __forceinline__ float bf2f(US b){ return __uint_as_float(((unsigned)b)<<16); }

// ---------------- init (ws is re-poisoned 0xAA before every call) ----------------
__global__ __launch_bounds__(256) void k_init(unsigned* __restrict__ mm, unsigned* __restrict__ counts,
    float* __restrict__ stat0, float* __restrict__ sum1, float* __restrict__ S1,
    float* __restrict__ sum2, float* __restrict__ S2) {
  int i = blockIdx.x*256 + threadIdx.x;
  if (i<6) mm[i] = (i<3)? 0xFFFFFFFFu : 0u;
  if (i<NB3*4) counts[i]=0u;
  if (i<14) stat0[i]=0.f;
  if (i<64) sum1[i]=0.f;
  if (i<4096) S1[i]=0.f;
  if (i<128) sum2[i]=0.f;
  if (i<16384) S2[i]=0.f;
}

// ---------------- global per-axis min/max ----------------
__global__ __launch_bounds__(256) void k_minmax(const float* __restrict__ pc, unsigned* __restrict__ mm, int npts) {
  int tid = threadIdx.x;
  int gid = blockIdx.x*256+tid, stride = gridDim.x*256;
  float mn0=3.4e38f,mn1=3.4e38f,mn2=3.4e38f, mx0=-3.4e38f,mx1=-3.4e38f,mx2=-3.4e38f;
  for (int p=gid;p<npts;p+=stride){
    float a=pc[3*p], b=pc[3*p+1], c=pc[3*p+2];
    mn0=fminf(mn0,a); mx0=fmaxf(mx0,a);
    mn1=fminf(mn1,b); mx1=fmaxf(mx1,b);
    mn2=fminf(mn2,c); mx2=fmaxf(mx2,c);
  }
  __shared__ float red[256];
  float v[6] = {mn0,mn1,mn2,mx0,mx1,mx2};
  #pragma unroll
  for (int q=0;q<6;q++){
    red[tid]=v[q]; __syncthreads();
    for (int st=128;st;st>>=1){ if (tid<st) red[tid] = (q<3)? fminf(red[tid],red[tid+st]) : fmaxf(red[tid],red[tid+st]); __syncthreads(); }
    if (tid==0){ if (q<3) atomicMin(&mm[q], fenc(red[0])); else atomicMax(&mm[q], fenc(red[0])); }
    __syncthreads();
  }
}

// shared binning (identical in all consumers; IEEE f32 matches numpy bit-exactly:
// step=(max-min)/32 is exact, then floor((x-min)/step))
__device__ __forceinline__ void get_mm(const unsigned* __restrict__ mm, float* mins, float* step){
  #pragma unroll
  for (int a=0;a<3;a++){ float mn=fdec(mm[a]), mx=fdec(mm[3+a]); mins[a]=mn; step[a]=(mx-mn)*(1.0f/HB); }
}
__device__ __forceinline__ int vox(const float* __restrict__ pc, int p, const float* mins, const float* step, float* v){
  float v0 = floorf((pc[3*p+0]-mins[0])/step[0]);
  float v1 = floorf((pc[3*p+1]-mins[1])/step[1]);
  float v2 = floorf((pc[3*p+2]-mins[2])/step[2]);
  v[0]=v0; v[1]=v1; v[2]=v2;
  return ((int)v0*NBv + (int)v1)*NBv + (int)v2;
}

// ---------------- per-(batch,voxel) histogram ----------------
__global__ __launch_bounds__(256) void k_hist(const float* __restrict__ pc, const unsigned* __restrict__ mm,
    unsigned* __restrict__ counts, int npts, int perB) {
  int p = blockIdx.x*256+threadIdx.x; if (p>=npts) return;
  float mins[3], step[3]; get_mm(mm,mins,step);
  float v[3]; int id = vox(pc,p,mins,step,v);
  atomicAdd(&counts[(p/perB)*NB3 + id], 1u);
}

// ---------------- x0 = [v,count] first+second moments (for BN1 fold) ----------------
__global__ __launch_bounds__(256) void k_embedstats(const float* __restrict__ pc, const unsigned* __restrict__ mm,
    const unsigned* __restrict__ counts, float* __restrict__ stat0, int npts, int perB) {
  int tid=threadIdx.x; int gid=blockIdx.x*256+tid, stride=gridDim.x*256;
  float mins[3], step[3]; get_mm(mm,mins,step);
  float s0=0,s1=0,s2=0,s3=0;
  float P[10]={0,0,0,0,0,0,0,0,0,0};
  for (int p=gid;p<npts;p+=stride){
    float v[3]; int id=vox(pc,p,mins,step,v);
    float x0=v[0],x1=v[1],x2=v[2],x3=(float)counts[(p/perB)*NB3+id];
    s0+=x0; s1+=x1; s2+=x2; s3+=x3;
    P[0]+=x0*x0; P[1]+=x0*x1; P[2]+=x0*x2; P[3]+=x0*x3;
    P[4]+=x1*x1; P[5]+=x1*x2; P[6]+=x1*x3;
    P[7]+=x2*x2; P[8]+=x2*x3; P[9]+=x3*x3;
  }
  __shared__ float red[256];
  float vals[14]={s0,s1,s2,s3,P[0],P[1],P[2],P[3],P[4],P[5],P[6],P[7],P[8],P[9]};
  #pragma unroll
  for (int q=0;q<14;q++){
    red[tid]=vals[q]; __syncthreads();
    for (int st=128;st;st>>=1){ if(tid<st) red[tid]+=red[tid+st]; __syncthreads(); }
    if (!tid) atomicAdd(&stat0[q], red[0]);
    __syncthreads();
  }
}

// ---------------- fold BN1: A1=s*W1 (f32), c1=beta1-s*(W1 mu) ----------------
__global__ __launch_bounds__(64) void k_stats1(const float* __restrict__ stat0, const float* __restrict__ W1,
    const float* __restrict__ b1, const float* __restrict__ g1, const float* __restrict__ be1,
    float* __restrict__ A1, float* __restrict__ c1, int npts) {
  int o = threadIdx.x;
  float inv = 1.0f/(float)npts;
  float mu0=stat0[0]*inv, mu1=stat0[1]*inv, mu2=stat0[2]*inv, mu3=stat0[3]*inv;
  float w0=W1[o*4],w1=W1[o*4+1],w2=W1[o*4+2],w3=W1[o*4+3];
  float wmu = w0*mu0+w1*mu1+w2*mu2+w3*mu3;
  const float* T = stat0+4;
  float q = w0*w0*T[0] + 2.f*w0*w1*T[1] + 2.f*w0*w2*T[2] + 2.f*w0*w3*T[3]
          + w1*w1*T[4] + 2.f*w1*w2*T[5] + 2.f*w1*w3*T[6]
          + w2*w2*T[7] + 2.f*w2*w3*T[8] + w3*w3*T[9];
  float var = q*inv - wmu*wmu;
  float s = g1[o]*rsqrtf(var+BN_EPS);
  A1[o*4]=s*w0; A1[o*4+1]=s*w1; A1[o*4+2]=s*w2; A1[o*4+3]=s*w3;
  c1[o] = be1[o] - s*wmu;
}

// ---------------- layer1: x1 = relu(A1 x0 + c1), thread per point ----------------
__global__ __launch_bounds__(256) void k_layer1(const float* __restrict__ pc, const unsigned* __restrict__ mm,
    const unsigned* __restrict__ counts, const float* __restrict__ A1, const float* __restrict__ c1,
    US* __restrict__ x1, int npts, int perB) {
  __shared__ float sA[256]; __shared__ float sc[64];
  int tid=threadIdx.x;
  sA[tid]=A1[tid]; if (tid<64) sc[tid]=c1[tid];
  __syncthreads();
  int p = blockIdx.x*256+tid; if (p>=npts) return;
  float mins[3], step[3]; get_mm(mm,mins,step);
  float v[3]; int id=vox(pc,p,mins,step,v);
  float cnt=(float)counts[(p/perB)*NB3+id];
  float a0=v[0],a1=v[1],a2=v[2],a3=cnt;
  __align__(16) US ob[64];
  #pragma unroll
  for (int o=0;o<64;o++){
    float y = sc[o] + sA[o*4]*a0 + sA[o*4+1]*a1 + sA[o*4+2]*a2 + sA[o*4+3]*a3;
    ob[o]=f2bf(fmaxf(y,0.f));
  }
  uint4* dst=(uint4*)&x1[(size_t)p*64];
  const uint4* sb=(const uint4*)ob;
  #pragma unroll
  for (int i=0;i<8;i++) dst[i]=sb[i];
}

// ---------------- transpose [M][C]->[C][M] + per-channel sum ----------------
template<int C>
__global__ __launch_bounds__(256) void k_transpose(const US* __restrict__ X, US* __restrict__ XT,
    float* __restrict__ sums, int M) {
  __shared__ US tile[64][74];        // 74 -> row stride 37 dwords (odd): <=2-way conflicts
  constexpr int TC = C/64;
  int bt = blockIdx.x;
  int pb = (bt/TC)*64, cb = (bt%TC)*64;
  int t = threadIdx.x;
  #pragma unroll
  for (int i=0;i<4;i++){
    int idx = t*4 + i*1024; int p = idx>>6, c = idx&63;
    const US* src = &X[(size_t)(pb+p)*C + cb + c];
    ushort2 v0 = *(const ushort2*)src; ushort2 v1 = *(const ushort2*)(src+2);
    tile[p][c]=v0.x; tile[p][c+1]=v0.y; tile[p][c+2]=v1.x; tile[p][c+3]=v1.y;
  }
  __syncthreads();
  int cc = t>>2, g = t&3;
  float s = 0.f;
  __align__(16) US buf[16];
  #pragma unroll
  for (int q=0;q<16;q++){ buf[q]=tile[g*16+q][cc]; s += bf2f(buf[q]); }
  US* dst = &XT[(size_t)(cb+cc)*M + pb + g*16];
  ((uint4*)dst)[0]=((const uint4*)buf)[0];
  ((uint4*)dst)[1]=((const uint4*)buf)[1];
  s += __shfl_down(s,1); s += __shfl_down(s,2);
  if (g==0) atomicAdd(&sums[cb+cc], s);
}

// ---------------- Gram S = X^T X via MFMA; both frags read rows of XT ----------------
template<int C, int IT>
__global__ __launch_bounds__(256) void k_cov(const US* __restrict__ XT, float* __restrict__ S, int M, int kpb) {
  constexpr int JT = C/16;
  int w = threadIdx.x>>6, lane = threadIdx.x&63;
  int r = lane&15, h = lane>>4;
  int k0 = blockIdx.x*kpb;
  f32x4 acc[IT][JT];
  #pragma unroll
  for (int it=0;it<IT;it++)
    #pragma unroll
    for (int jt=0;jt<JT;jt++) acc[it][jt]=f32x4{0.f,0.f,0.f,0.f};
  for (int kk=0; kk<kpb; kk+=32){
    int kb = k0 + kk + h*8;
    short8 a[IT], b[JT];
    #pragma unroll
    for (int it=0;it<IT;it++) a[it] = *(const short8*)&XT[(size_t)((w+it*4)*16 + r)*M + kb];
    #pragma unroll
    for (int jt=0;jt<JT;jt++) b[jt] = *(const short8*)&XT[(size_t)(jt*16 + r)*M + kb];
    #pragma unroll
    for (int it=0;it<IT;it++)
      #pragma unroll
      for (int jt=0;jt<JT;jt++)
        acc[it][jt] = __builtin_amdgcn_mfma_f32_16x16x32_bf16(a[it], b[jt], acc[it][jt], 0,0,0);
  }
  #pragma unroll
  for (int it=0;it<IT;it++)
    #pragma unroll
    for (int jt=0;jt<JT;jt++)
      #pragma unroll
      for (int j=0;j<4;j++)
        atomicAdd(&S[((w+it*4)*16 + h*4 + j)*C + jt*16 + r], acc[it][jt][j]);
}

// ---------------- fold BN2: A2 bf16 [128][64], c2 ----------------
__global__ __launch_bounds__(64) void k_stats2(const float* __restrict__ sum1, const float* __restrict__ S1,
    const float* __restrict__ W2, const float* __restrict__ b2, const float* __restrict__ g2, const float* __restrict__ be2,
    US* __restrict__ A2, float* __restrict__ c2, int npts) {
  int o = blockIdx.x, t = threadIdx.x;
  __shared__ float sw[64];
  sw[t] = W2[o*64+t];
  __syncthreads();
  float inv = 1.0f/(float)npts;
  float wi = sw[t];
  float d=0.f;
  #pragma unroll 8
  for (int j=0;j<64;j++) d += S1[t*64+j]*sw[j];
  float part = wi*d;
  float wmup = wi*sum1[t]*inv;
  #pragma unroll
  for (int off=32;off;off>>=1){ part+=__shfl_down(part,off); wmup+=__shfl_down(wmup,off); }
  float q = __shfl(part,0), wmu = __shfl(wmup,0);
  float var = q*inv - wmu*wmu;
  float s = g2[o]*rsqrtf(var+BN_EPS);
  A2[o*64+t] = f2bf(s*sw[t]);
  if (t==0) c2[o] = be2[o] - s*wmu;
}

// ---------------- fold BN3: A3 bf16 [1024][128], c3 ----------------
__global__ __launch_bounds__(128) void k_stats3(const float* __restrict__ sum2, const float* __restrict__ S2,
    const float* __restrict__ W3, const float* __restrict__ b3, const float* __restrict__ g3, const float* __restrict__ be3,
    US* __restrict__ A3, float* __restrict__ c3, int npts) {
  int o = blockIdx.x, t = threadIdx.x;
  __shared__ float sw[128], red[128], red2[128];
  sw[t] = W3[o*128+t];
  __syncthreads();
  float inv = 1.0f/(float)npts;
  float wi = sw[t];
  float d=0.f;
  #pragma unroll 8
  for (int j=0;j<128;j++) d += S2[t*128+j]*sw[j];
  red[t] = wi*d; red2[t] = wi*sum2[t]*inv;
  __syncthreads();
  for (int st=64; st; st>>=1){ if (t<st){ red[t]+=red[t+st]; red2[t]+=red2[t+st]; } __syncthreads(); }
  float q = red[0], wmu = red2[0];
  float var = q*inv - wmu*wmu;
  float s = g3[o]*rsqrtf(var+BN_EPS);
  A3[o*128+t] = f2bf(s*sw[t]);
  if (t==0) c3[o] = be3[o] - s*wmu;
}

// ---------------- fused matmul + BN-affine + relu (bf16 MFMA) ----------------
// X [M][K] bf16, Wf [NOUT][K] bf16 (BN-folded), out = relu(X Wf^T + c)
template<int K, int NT, int NOUT, bool OUTBF16>
__global__ __launch_bounds__(256) void k_gemm(const US* __restrict__ X, const US* __restrict__ Wf,
    const float* __restrict__ cvec, void* __restrict__ outp, int M) {
  constexpr int G = NOUT/(16*NT);
  int wid = (blockIdx.x*256 + threadIdx.x)>>6;
  int lane = threadIdx.x&63;
  int ptTile = wid / G, cg = wid % G;
  int ptbase = ptTile*16, obase = cg*16*NT;
  int r = lane&15, h = lane>>4;
  f32x4 acc[NT];
  #pragma unroll
  for (int t=0;t<NT;t++) acc[t]=f32x4{0.f,0.f,0.f,0.f};
  const US* arow = X + (size_t)(ptbase + r)*K + h*8;
  #pragma unroll
  for (int k=0;k<K;k+=32){
    short8 a = *(const short8*)(arow + k);
    #pragma unroll
    for (int t=0;t<NT;t++){
      short8 b = *(const short8*)(Wf + (size_t)(obase + t*16 + r)*K + k + h*8);
      acc[t] = __builtin_amdgcn_mfma_f32_16x16x32_bf16(a, b, acc[t], 0,0,0);
    }
  }
  #pragma unroll
  for (int t=0;t<NT;t++){
    int col = obase + t*16 + r;
    float ct = cvec[col];
    #pragma unroll
    for (int j=0;j<4;j++){
      int row = ptbase + h*4 + j;
      float vv = fmaxf(acc[t][j]+ct, 0.f);
      if (OUTBF16) ((US*)outp)[(size_t)row*NOUT+col] = f2bf(vv);
      else        ((float*)outp)[(size_t)row*NOUT+col] = vv;
    }
  }
}

extern "C" void kernel_launch(void* const* d_in, const int* in_sizes, int n_in,
                              void* d_out, int out_size, void* d_ws, size_t ws_size,
                              hipStream_t stream) {
  const float* pc  = (const float*)d_in[0];
  const float* W1  = (const float*)d_in[1];  const float* b1 = (const float*)d_in[2];
  const float* g1  = (const float*)d_in[3];  const float* be1= (const float*)d_in[4];
  const float* W2  = (const float*)d_in[5];  const float* b2 = (const float*)d_in[6];
  const float* g2  = (const float*)d_in[7];  const float* be2= (const float*)d_in[8];
  const float* W3  = (const float*)d_in[9];  const float* b3 = (const float*)d_in[10];
  const float* g3  = (const float*)d_in[11]; const float* be3= (const float*)d_in[12];
  int npts = in_sizes[0]/3;        // 131072
  int perB = npts/4;               // 32768

  char* ws = (char*)d_ws;
  size_t off = 0;
  auto alloc = [&](size_t bytes){ size_t o = off; off = (off + bytes + 255) & ~(size_t)255; return o; };
  unsigned* mm     = (unsigned*)(ws + alloc(6*4));
  unsigned* counts = (unsigned*)(ws + alloc((size_t)4*NB3*4));
  float* stat0 = (float*)(ws + alloc(14*4));
  float* A1    = (float*)(ws + alloc(256*4));
  float* c1    = (float*)(ws + alloc(64*4));
  float* sum1  = (float*)(ws + alloc(64*4));
  float* S1    = (float*)(ws + alloc(4096*4));
  US*    A2    = (US*)(ws + alloc(8192*2));
  float* c2    = (float*)(ws + alloc(128*4));
  float* sum2  = (float*)(ws + alloc(128*4));
  float* S2    = (float*)(ws + alloc(16384*4));
  US*    A3    = (US*)(ws + alloc(131072*2));
  float* c3    = (float*)(ws + alloc(1024*4));
  US* x1  = (US*)(ws + alloc((size_t)npts*64*2));
  US* x1T = (US*)(ws + alloc((size_t)npts*64*2));
  US* x2  = (US*)(ws + alloc((size_t)npts*128*2));
  US* x2T = (US*)(ws + alloc((size_t)npts*128*2));

  int pblk = (npts+255)/256;

  k_init<<<(NB3*4+255)/256,256,0,stream>>>(mm,counts,stat0,sum1,S1,sum2,S2);
  k_minmax<<<256,256,0,stream>>>(pc,mm,npts);
  k_hist<<<pblk,256,0,stream>>>(pc,mm,counts,npts,perB);
  k_embedstats<<<256,256,0,stream>>>(pc,mm,counts,stat0,npts,perB);
  k_stats1<<<1,64,0,stream>>>(stat0,W1,b1,g1,be1,A1,c1,npts);
  k_layer1<<<pblk,256,0,stream>>>(pc,mm,counts,A1,c1,x1,npts,perB);
  k_transpose<64><<<npts/64,256,0,stream>>>(x1,x1T,sum1,npts);
  k_cov<64,1><<<32,256,0,stream>>>(x1T,S1,npts,npts/32);
  k_stats2<<<128,64,0,stream>>>(sum1,S1,W2,b2,g2,be2,A2,c2,npts);
  k_gemm<64,4,128,true><<<(npts/16)*2/4,256,0,stream>>>(x1,A2,c2,x2,npts);
  k_transpose<128><<<(npts/64)*2,256,0,stream>>>(x2,x2T,sum2,npts);
  k_cov<128,2><<<32,256,0,stream>>>(x2T,S2,npts,npts/32);
  k_stats3<<<1024,128,0,stream>>>(sum2,S2,W3,b3,g3,be3,A3,c3,npts);
  k_gemm<128,8,1024,false><<<(npts/16)*8/4,256,0,stream>>>(x2,A3,c3,(float*)d_out,npts);
}

// Round 3
// 1011.834 us; speedup vs baseline: 1.2083x; 1.2083x over previous
//
#include <hip/hip_runtime.h>

#define HB 32
#define NBv 33
#define NB3 35937
#define BN_EPS 1e-5f

using short8 = __attribute__((ext_vector_type(8))) short;
using f32x4  = __attribute__((ext_vector_type(4))) float;
using US = unsigned short;

#define GL_LDS16(gp, lp) __builtin_amdgcn_global_load_lds( \
    (const __attribute__((address_space(1))) unsigned int*)(gp), \
    (__attribute__((address_space(3))) unsigned int*)(lp), 16, 0, 0)

__device__ __forceinline__ unsigned fenc(float f){ unsigned u=__float_as_uint(f); return (u&0x80000000u)? ~u : (u|0x80000000u); }
__device__ __forceinline__ float fdec(unsigned e){ return (e&0x80000000u)? __uint_as_float(e&0x7fffffffu) : __uint_as_float(~e); }
__device__ __forceinline__ US f2bf(float f){ unsigned u=__float_as_uint(f); return (US)((u + 0x7fffu + ((u>>16)&1u))>>16); }
__device__ __forceinline__ float bf2f(US b){ return __uint_as_float(((unsigned)b)<<16); }

// ---------------- init ----------------
__global__ __launch_bounds__(256) void k_init(unsigned* __restrict__ mm, unsigned* __restrict__ counts,
    float* __restrict__ stat0, float* __restrict__ sum1, float* __restrict__ sum2) {
  int i = blockIdx.x*256 + threadIdx.x;
  if (i<6) mm[i] = (i<3)? 0xFFFFFFFFu : 0u;
  if (i<NB3*4) counts[i]=0u;
  if (i<14) stat0[i]=0.f;
  if (i<64) sum1[i]=0.f;
  if (i<128) sum2[i]=0.f;
}

// ---------------- global per-axis min/max ----------------
__global__ __launch_bounds__(256) void k_minmax(const float* __restrict__ pc, unsigned* __restrict__ mm, int npts) {
  int tid = threadIdx.x;
  int gid = blockIdx.x*256+tid, stride = gridDim.x*256;
  float mn0=3.4e38f,mn1=3.4e38f,mn2=3.4e38f, mx0=-3.4e38f,mx1=-3.4e38f,mx2=-3.4e38f;
  for (int p=gid;p<npts;p+=stride){
    float a=pc[3*p], b=pc[3*p+1], c=pc[3*p+2];
    mn0=fminf(mn0,a); mx0=fmaxf(mx0,a);
    mn1=fminf(mn1,b); mx1=fmaxf(mx1,b);
    mn2=fminf(mn2,c); mx2=fmaxf(mx2,c);
  }
  __shared__ float red[256];
  float v[6] = {mn0,mn1,mn2,mx0,mx1,mx2};
  #pragma unroll
  for (int q=0;q<6;q++){
    red[tid]=v[q]; __syncthreads();
    for (int st=128;st;st>>=1){ if (tid<st) red[tid] = (q<3)? fminf(red[tid],red[tid+st]) : fmaxf(red[tid],red[tid+st]); __syncthreads(); }
    if (tid==0){ if (q<3) atomicMin(&mm[q], fenc(red[0])); else atomicMax(&mm[q], fenc(red[0])); }
    __syncthreads();
  }
}

// shared binning (IEEE f32 matches numpy bit-exactly: step=(max-min)/32 exact, floor((x-min)/step))
__device__ __forceinline__ void get_mm(const unsigned* __restrict__ mm, float* mins, float* step){
  #pragma unroll
  for (int a=0;a<3;a++){ float mn=fdec(mm[a]), mx=fdec(mm[3+a]); mins[a]=mn; step[a]=(mx-mn)*(1.0f/HB); }
}
__device__ __forceinline__ int vox(const float* __restrict__ pc, int p, const float* mins, const float* step, float* v){
  float v0 = floorf((pc[3*p+0]-mins[0])/step[0]);
  float v1 = floorf((pc[3*p+1]-mins[1])/step[1]);
  float v2 = floorf((pc[3*p+2]-mins[2])/step[2]);
  v[0]=v0; v[1]=v1; v[2]=v2;
  return ((int)v0*NBv + (int)v1)*NBv + (int)v2;
}

// ---------------- per-(batch,voxel) histogram ----------------
__global__ __launch_bounds__(256) void k_hist(const float* __restrict__ pc, const unsigned* __restrict__ mm,
    unsigned* __restrict__ counts, int npts, int perB) {
  int p = blockIdx.x*256+threadIdx.x; if (p>=npts) return;
  float mins[3], step[3]; get_mm(mm,mins,step);
  float v[3]; int id = vox(pc,p,mins,step,v);
  atomicAdd(&counts[(p/perB)*NB3 + id], 1u);
}

// ---------------- x0 moments (for BN1 fold) ----------------
__global__ __launch_bounds__(256) void k_embedstats(const float* __restrict__ pc, const unsigned* __restrict__ mm,
    const unsigned* __restrict__ counts, float* __restrict__ stat0, int npts, int perB) {
  int tid=threadIdx.x; int gid=blockIdx.x*256+tid, stride=gridDim.x*256;
  float mins[3], step[3]; get_mm(mm,mins,step);
  float s0=0,s1=0,s2=0,s3=0;
  float P[10]={0,0,0,0,0,0,0,0,0,0};
  for (int p=gid;p<npts;p+=stride){
    float v[3]; int id=vox(pc,p,mins,step,v);
    float x0=v[0],x1=v[1],x2=v[2],x3=(float)counts[(p/perB)*NB3+id];
    s0+=x0; s1+=x1; s2+=x2; s3+=x3;
    P[0]+=x0*x0; P[1]+=x0*x1; P[2]+=x0*x2; P[3]+=x0*x3;
    P[4]+=x1*x1; P[5]+=x1*x2; P[6]+=x1*x3;
    P[7]+=x2*x2; P[8]+=x2*x3; P[9]+=x3*x3;
  }
  __shared__ float red[256];
  float vals[14]={s0,s1,s2,s3,P[0],P[1],P[2],P[3],P[4],P[5],P[6],P[7],P[8],P[9]};
  #pragma unroll
  for (int q=0;q<14;q++){
    red[tid]=vals[q]; __syncthreads();
    for (int st=128;st;st>>=1){ if(tid<st) red[tid]+=red[tid+st]; __syncthreads(); }
    if (!tid) atomicAdd(&stat0[q], red[0]);
    __syncthreads();
  }
}

// ---------------- fold BN1 ----------------
__global__ __launch_bounds__(64) void k_stats1(const float* __restrict__ stat0, const float* __restrict__ W1,
    const float* __restrict__ b1, const float* __restrict__ g1, const float* __restrict__ be1,
    float* __restrict__ A1, float* __restrict__ c1, int npts) {
  int o = threadIdx.x;
  float inv = 1.0f/(float)npts;
  float mu0=stat0[0]*inv, mu1=stat0[1]*inv, mu2=stat0[2]*inv, mu3=stat0[3]*inv;
  float w0=W1[o*4],w1=W1[o*4+1],w2=W1[o*4+2],w3=W1[o*4+3];
  float wmu = w0*mu0+w1*mu1+w2*mu2+w3*mu3;
  const float* T = stat0+4;
  float q = w0*w0*T[0] + 2.f*w0*w1*T[1] + 2.f*w0*w2*T[2] + 2.f*w0*w3*T[3]
          + w1*w1*T[4] + 2.f*w1*w2*T[5] + 2.f*w1*w3*T[6]
          + w2*w2*T[7] + 2.f*w2*w3*T[8] + w3*w3*T[9];
  float var = q*inv - wmu*wmu;
  float s = g1[o]*rsqrtf(var+BN_EPS);
  A1[o*4]=s*w0; A1[o*4+1]=s*w1; A1[o*4+2]=s*w2; A1[o*4+3]=s*w3;
  c1[o] = be1[o] - s*wmu;
}

// ---------------- layer1 ----------------
__global__ __launch_bounds__(256) void k_layer1(const float* __restrict__ pc, const unsigned* __restrict__ mm,
    const unsigned* __restrict__ counts, const float* __restrict__ A1, const float* __restrict__ c1,
    US* __restrict__ x1, int npts, int perB) {
  __shared__ float sA[256]; __shared__ float sc[64];
  int tid=threadIdx.x;
  sA[tid]=A1[tid]; if (tid<64) sc[tid]=c1[tid];
  __syncthreads();
  int p = blockIdx.x*256+tid; if (p>=npts) return;
  float mins[3], step[3]; get_mm(mm,mins,step);
  float v[3]; int id=vox(pc,p,mins,step,v);
  float cnt=(float)counts[(p/perB)*NB3+id];
  float a0=v[0],a1=v[1],a2=v[2],a3=cnt;
  __align__(16) US ob[64];
  #pragma unroll
  for (int o=0;o<64;o++){
    float y = sc[o] + sA[o*4]*a0 + sA[o*4+1]*a1 + sA[o*4+2]*a2 + sA[o*4+3]*a3;
    ob[o]=f2bf(fmaxf(y,0.f));
  }
  uint4* dst=(uint4*)&x1[(size_t)p*64];
  const uint4* sb=(const uint4*)ob;
  #pragma unroll
  for (int i=0;i<8;i++) dst[i]=sb[i];
}

// ---------------- transpose [M][C]->[C][M] + per-channel sum ----------------
template<int C>
__global__ __launch_bounds__(256) void k_transpose(const US* __restrict__ X, US* __restrict__ XT,
    float* __restrict__ sums, int M) {
  __shared__ US tile[64][74];
  constexpr int TC = C/64;
  int bt = blockIdx.x;
  int pb = (bt/TC)*64, cb = (bt%TC)*64;
  int t = threadIdx.x;
  #pragma unroll
  for (int i=0;i<4;i++){
    int idx = t*4 + i*1024; int p = idx>>6, c = idx&63;
    const US* src = &X[(size_t)(pb+p)*C + cb + c];
    ushort2 v0 = *(const ushort2*)src; ushort2 v1 = *(const ushort2*)(src+2);
    tile[p][c]=v0.x; tile[p][c+1]=v0.y; tile[p][c+2]=v1.x; tile[p][c+3]=v1.y;
  }
  __syncthreads();
  int cc = t>>2, g = t&3;
  float s = 0.f;
  __align__(16) US buf[16];
  #pragma unroll
  for (int q=0;q<16;q++){ buf[q]=tile[g*16+q][cc]; s += bf2f(buf[q]); }
  US* dst = &XT[(size_t)(cb+cc)*M + pb + g*16];
  ((uint4*)dst)[0]=((const uint4*)buf)[0];
  ((uint4*)dst)[1]=((const uint4*)buf)[1];
  s += __shfl_down(s,1); s += __shfl_down(s,2);
  if (g==0) atomicAdd(&sums[cb+cc], s);
}

// ---------------- Gram partials: P[blk] = X^T X over this block's K-chunk ----------------
template<int C, int NW>
__global__ __launch_bounds__(NW*64) void k_cov(const US* __restrict__ XT, float* __restrict__ P, int M, int kpb) {
  constexpr int JT = C/16;
  int w = threadIdx.x>>6, lane = threadIdx.x&63;
  int r = lane&15, h = lane>>4;
  int k0 = blockIdx.x*kpb;
  f32x4 acc[JT];
  #pragma unroll
  for (int jt=0;jt<JT;jt++) acc[jt]=f32x4{0.f,0.f,0.f,0.f};
  for (int kk=0; kk<kpb; kk+=32){
    int kb = k0 + kk + h*8;
    short8 a = *(const short8*)&XT[(size_t)(w*16 + r)*M + kb];
    #pragma unroll
    for (int jt=0;jt<JT;jt++){
      short8 b = *(const short8*)&XT[(size_t)(jt*16 + r)*M + kb];
      acc[jt] = __builtin_amdgcn_mfma_f32_16x16x32_bf16(a, b, acc[jt], 0,0,0);
    }
  }
  float* Pb = P + (size_t)blockIdx.x*C*C;
  #pragma unroll
  for (int jt=0;jt<JT;jt++)
    #pragma unroll
    for (int j=0;j<4;j++)
      Pb[(w*16 + h*4 + j)*C + jt*16 + r] = acc[jt][j];
}

template<int C>
__global__ __launch_bounds__(256) void k_covred(const float* __restrict__ P, float* __restrict__ S, int nblk) {
  int i = blockIdx.x*256 + threadIdx.x;
  float s = 0.f;
  for (int b=0;b<nblk;b++) s += P[(size_t)b*C*C + i];
  S[i] = s;
}

// ---------------- fold BN2 (S1 symmetric -> coalesced reads) ----------------
__global__ __launch_bounds__(64) void k_stats2(const float* __restrict__ sum1, const float* __restrict__ S1,
    const float* __restrict__ W2, const float* __restrict__ b2, const float* __restrict__ g2, const float* __restrict__ be2,
    US* __restrict__ A2, float* __restrict__ c2, int npts) {
  int o = blockIdx.x, t = threadIdx.x;
  __shared__ float sw[64];
  sw[t] = W2[o*64+t];
  __syncthreads();
  float inv = 1.0f/(float)npts;
  float wi = sw[t];
  float d=0.f;
  #pragma unroll 8
  for (int j=0;j<64;j++) d += S1[j*64+t]*sw[j];
  float part = wi*d;
  float wmup = wi*sum1[t]*inv;
  #pragma unroll
  for (int off=32;off;off>>=1){ part+=__shfl_down(part,off); wmup+=__shfl_down(wmup,off); }
  float q = __shfl(part,0), wmu = __shfl(wmup,0);
  float var = q*inv - wmu*wmu;
  float s = g2[o]*rsqrtf(var+BN_EPS);
  A2[o*64+t] = f2bf(s*sw[t]);
  if (t==0) c2[o] = be2[o] - s*wmu;
}

// ---------------- fold BN3 (S2 symmetric -> coalesced reads) ----------------
__global__ __launch_bounds__(128) void k_stats3(const float* __restrict__ sum2, const float* __restrict__ S2,
    const float* __restrict__ W3, const float* __restrict__ b3, const float* __restrict__ g3, const float* __restrict__ be3,
    US* __restrict__ A3, float* __restrict__ c3, int npts) {
  int o = blockIdx.x, t = threadIdx.x;
  __shared__ float sw[128], red[128], red2[128];
  sw[t] = W3[o*128+t];
  __syncthreads();
  float inv = 1.0f/(float)npts;
  float wi = sw[t];
  float d=0.f;
  #pragma unroll 8
  for (int j=0;j<128;j++) d += S2[j*128+t]*sw[j];
  red[t] = wi*d; red2[t] = wi*sum2[t]*inv;
  __syncthreads();
  for (int st=64; st; st>>=1){ if (t<st){ red[t]+=red[t+st]; red2[t]+=red2[t+st]; } __syncthreads(); }
  float q = red[0], wmu = red2[0];
  float var = q*inv - wmu*wmu;
  float s = g3[o]*rsqrtf(var+BN_EPS);
  A3[o*128+t] = f2bf(s*sw[t]);
  if (t==0) c3[o] = be3[o] - s*wmu;
}

// ---------------- tiled GEMM: 128x128 block tile, whole K in LDS ----------------
// X [M][K] bf16 row-major, Wf [OUTW][K] bf16 (BN-folded), out = relu(X Wf^T + c)
// LDS XOR-swizzle: LDS[row][chunk] holds global[row][chunk ^ (row&CHM)]
// (linear LDS dest for global_load_lds + pre-swizzled global src + swizzled ds_read)
template<int K, int OUTW, bool OUTBF16>
__global__ __launch_bounds__(256) void k_tgemm(const US* __restrict__ X, const US* __restrict__ Wf,
    const float* __restrict__ cvec, void* __restrict__ outp, int M) {
  constexpr int NG  = OUTW/128;          // col groups of 128
  constexpr int RS  = K*2;               // row stride bytes in tile
  constexpr int CHM = K/8 - 1;           // 16B-chunk mask per row
  constexpr int NQ  = (128*K*2)/4096;    // global_load_lds issues per wave per tile
  __shared__ US lds[2*128*K];
  US* ldsA = lds; US* ldsB = lds + 128*K;
  int tid = threadIdx.x, l = tid&63, w = tid>>6;
  int og = blockIdx.x % NG, mb = blockIdx.x / NG;
  const US* Asrc = X  + (size_t)mb*128*K;
  const US* Bsrc = Wf + (size_t)og*128*K;
  #pragma unroll
  for (int q=0;q<NQ;q++){
    unsigned B = ((unsigned)(q*4+w)<<10) + ((unsigned)l<<4);
    unsigned r = B / RS;
    unsigned cs = ((B>>4)&CHM) ^ (r & CHM);
    GL_LDS16(Asrc + r*K + cs*8, ldsA + (q*4+w)*512);
    GL_LDS16(Bsrc + r*K + cs*8, ldsB + (q*4+w)*512);
  }
  __syncthreads();
  int rbw = (w>>1)*64, cbw = (w&1)*64;
  int r16 = l&15, hq = l>>4;
  f32x4 acc[4][4];
  #pragma unroll
  for (int i=0;i<4;i++)
    #pragma unroll
    for (int j=0;j<4;j++) acc[i][j]=f32x4{0.f,0.f,0.f,0.f};
  #pragma unroll
  for (int ks=0; ks<K/32; ks++){
    short8 af[4], bf[4];
    int ca = ks*4 + hq;
    #pragma unroll
    for (int f=0; f<4; f++){
      int Ra = rbw + f*16 + r16;
      af[f] = *(const short8*)&ldsA[Ra*K + ((ca ^ (Ra&CHM))<<3)];
      int Rb = cbw + f*16 + r16;
      bf[f] = *(const short8*)&ldsB[Rb*K + ((ca ^ (Rb&CHM))<<3)];
    }
    #pragma unroll
    for (int fi=0;fi<4;fi++)
      #pragma unroll
      for (int fj=0;fj<4;fj++)
        acc[fi][fj] = __builtin_amdgcn_mfma_f32_16x16x32_bf16(af[fi], bf[fj], acc[fi][fj], 0,0,0);
  }
  #pragma unroll
  for (int fj=0;fj<4;fj++){
    int col = og*128 + cbw + fj*16 + r16;
    float cv = cvec[col];
    #pragma unroll
    for (int fi=0;fi<4;fi++){
      #pragma unroll
      for (int j=0;j<4;j++){
        int row = mb*128 + rbw + fi*16 + hq*4 + j;
        float v = fmaxf(acc[fi][fj][j]+cv, 0.f);
        if (OUTBF16) ((US*)outp)[(size_t)row*OUTW+col] = f2bf(v);
        else        ((float*)outp)[(size_t)row*OUTW+col] = v;
      }
    }
  }
}

extern "C" void kernel_launch(void* const* d_in, const int* in_sizes, int n_in,
                              void* d_out, int out_size, void* d_ws, size_t ws_size,
                              hipStream_t stream) {
  const float* pc  = (const float*)d_in[0];
  const float* W1  = (const float*)d_in[1];  const float* b1 = (const float*)d_in[2];
  const float* g1  = (const float*)d_in[3];  const float* be1= (const float*)d_in[4];
  const float* W2  = (const float*)d_in[5];  const float* b2 = (const float*)d_in[6];
  const float* g2  = (const float*)d_in[7];  const float* be2= (const float*)d_in[8];
  const float* W3  = (const float*)d_in[9];  const float* b3 = (const float*)d_in[10];
  const float* g3  = (const float*)d_in[11]; const float* be3= (const float*)d_in[12];
  int npts = in_sizes[0]/3;        // 131072
  int perB = npts/4;               // 32768
  const int NCOV = 256;            // K-split blocks for Gram partials

  char* ws = (char*)d_ws;
  size_t off = 0;
  auto alloc = [&](size_t bytes){ size_t o = off; off = (off + bytes + 255) & ~(size_t)255; return o; };
  unsigned* mm     = (unsigned*)(ws + alloc(6*4));
  unsigned* counts = (unsigned*)(ws + alloc((size_t)4*NB3*4));
  float* stat0 = (float*)(ws + alloc(14*4));
  float* A1    = (float*)(ws + alloc(256*4));
  float* c1    = (float*)(ws + alloc(64*4));
  float* sum1  = (float*)(ws + alloc(64*4));
  float* S1    = (float*)(ws + alloc(4096*4));
  US*    A2    = (US*)(ws + alloc(8192*2));
  float* c2    = (float*)(ws + alloc(128*4));
  float* sum2  = (float*)(ws + alloc(128*4));
  float* S2    = (float*)(ws + alloc(16384*4));
  US*    A3    = (US*)(ws + alloc(131072*2));
  float* c3    = (float*)(ws + alloc(1024*4));
  float* P1    = (float*)(ws + alloc((size_t)NCOV*4096*4));
  float* P2    = (float*)(ws + alloc((size_t)NCOV*16384*4));
  US* x1  = (US*)(ws + alloc((size_t)npts*64*2));
  US* x1T = (US*)(ws + alloc((size_t)npts*64*2));
  US* x2  = (US*)(ws + alloc((size_t)npts*128*2));
  US* x2T = (US*)(ws + alloc((size_t)npts*128*2));

  int pblk = (npts+255)/256;

  k_init<<<(NB3*4+255)/256,256,0,stream>>>(mm,counts,stat0,sum1,sum2);
  k_minmax<<<256,256,0,stream>>>(pc,mm,npts);
  k_hist<<<pblk,256,0,stream>>>(pc,mm,counts,npts,perB);
  k_embedstats<<<256,256,0,stream>>>(pc,mm,counts,stat0,npts,perB);
  k_stats1<<<1,64,0,stream>>>(stat0,W1,b1,g1,be1,A1,c1,npts);
  k_layer1<<<pblk,256,0,stream>>>(pc,mm,counts,A1,c1,x1,npts,perB);
  k_transpose<64><<<npts/64,256,0,stream>>>(x1,x1T,sum1,npts);
  k_cov<64,4><<<NCOV,256,0,stream>>>(x1T,P1,npts,npts/NCOV);
  k_covred<64><<<16,256,0,stream>>>(P1,S1,NCOV);
  k_stats2<<<128,64,0,stream>>>(sum1,S1,W2,b2,g2,be2,A2,c2,npts);
  k_tgemm<64,128,true><<<npts/128,256,0,stream>>>(x1,A2,c2,x2,npts);
  k_transpose<128><<<(npts/64)*2,256,0,stream>>>(x2,x2T,sum2,npts);
  k_cov<128,8><<<NCOV,512,0,stream>>>(x2T,P2,npts,npts/NCOV);
  k_covred<128><<<64,256,0,stream>>>(P2,S2,NCOV);
  k_stats3<<<1024,128,0,stream>>>(sum2,S2,W3,b3,g3,be3,A3,c3,npts);
  k_tgemm<128,1024,false><<<(npts/128)*8,256,0,stream>>>(x2,A3,c3,(float*)d_out,npts);
}